// Round 2
// baseline (1127.734 us; speedup 1.0000x reference)
//
#include <hip/hip_runtime.h>
#include <hip/hip_bf16.h>

#define BB 8
#define SS 4096
#define DD 64
#define QT 32
#define KTILE 64
#define NKT (SS / KTILE)      // 64
#define NTHREADS 512

typedef __attribute__((ext_vector_type(4))) short short4v;
typedef __attribute__((ext_vector_type(8))) short short8v;
typedef __attribute__((ext_vector_type(4))) float float4v;

__device__ __forceinline__ unsigned short f2bf(float f) {
  union { __hip_bfloat16 b; unsigned short u; } cv;
  cv.b = __float2bfloat16(f);
  return cv.u;
}

__device__ __forceinline__ short4v pack4(const float4 v) {
  short4v p;
  p.x = (short)f2bf(v.x); p.y = (short)f2bf(v.y);
  p.z = (short)f2bf(v.z); p.w = (short)f2bf(v.w);
  return p;
}

// v3: occupancy 46% -> ~100%.
//  - QT 64->32, KTILE 128->64: LDS 62976 -> 37120 B, grid 512 -> 1024 blocks,
//    4 blocks/CU (32 waves/CU). __launch_bounds__(512,8) forces VGPR<=64.
//  - K double-buffered with 2-phase pipeline (issue loads early, write late):
//    1 barrier/kt in sweep1, 2 in sweep2 (was 2/3).
//  - mask bits still register-resident (8 VGPRs/lane); Bm overlays Ks0/Ks1.
__global__ __launch_bounds__(NTHREADS, 8)
void attn_fused_kernel(const float* __restrict__ Q, const float* __restrict__ K,
                       const float* __restrict__ V, const int* __restrict__ M,
                       float* __restrict__ Octx, float* __restrict__ Oattn) {
  __shared__ __align__(16) unsigned short Qs[QT][72];   // 4608 B
  // Pool: phase0 = Bm bitmask [QT*65] u64 (16640 B, overlays Ks0+part of Ks1);
  //       main   = Ks0 | Ks1 | Vt | Ps
  __shared__ __align__(16) unsigned char Pool[32256];
  __shared__ float RowSum[QT];
  __shared__ float InvRow[QT];

  typedef unsigned short Row72[72];                 // 144 B row stride (16B mult)
  Row72* Ks0 = (Row72*)Pool;                        //  9216 B [64][72]
  Row72* Ks1 = (Row72*)(Pool + 9216);               //  9216 B
  Row72* Vt  = (Row72*)(Pool + 18432);              //  9216 B [d][kk]
  Row72* Ps  = (Row72*)(Pool + 27648);              //  4608 B [32][72]
  unsigned long long* Bm = (unsigned long long*)Pool; // 32*65*8 = 16640 B, phase0 only

  const int tid  = threadIdx.x;
  const int w    = tid >> 6;
  const int lane = tid & 63;
  const int quad = lane >> 4;
  const int l15  = lane & 15;
  const int qs   = (w & 1) << 4;  // q-strip (16 rows)
  const int kq   = (w >> 1) << 4; // k-quarter (16 cols) for QK
  const int dq   = (w >> 1) << 4; // d-quarter (16 cols) for PV

  // batch-per-XCD swizzle: batch pinned to one XCD so its K+V (4 MB) stays in L2
  const int bb = blockIdx.x & 7;
  const int qt = blockIdx.x >> 3;
  const int q0 = qt * QT;

  const float* Qg = Q + ((size_t)bb * SS + q0) * DD;
  const float* Kg = K + (size_t)bb * SS * DD;
  const float* Vg = V + (size_t)bb * SS * DD;
  const int*   Mg = M + ((size_t)bb * SS + q0) * (size_t)SS;
  float* Ag = Oattn + ((size_t)bb * SS + q0) * (size_t)SS;
  float* Cg = Octx + ((size_t)bb * SS + q0) * DD;

  if (tid < QT) RowSum[tid] = 0.f;

  const int rK = tid >> 4, cK = (tid & 15) << 2;  // staging coords (dense 16B/lane)

  // K tile 0: issue global loads ASAP (LDS write deferred past the Bm phase)
  const float4 pk0A = *(const float4*)(Kg + (size_t)rK * DD + cK);
  const float4 pk0B = *(const float4*)(Kg + (size_t)(32 + rK) * DD + cK);

  // ---- Q tile -> LDS (bf16), single pass (512 items / 512 threads) ----
  {
    const float4 qv = *(const float4*)(Qg + (size_t)rK * DD + cK);
    *(short4v*)&Qs[rK][cK] = pack4(qv);
  }

  // ---- mask -> LDS bitmask (single coalesced HBM read of the mask) ----
  // word layout: Bm[row*65 + (c>>8)*4 + (c&3)], bit index (c>>2)&63
#pragma unroll 4
  for (int j = 0; j < 64; ++j) {
    const int it = (j << 3) | w;
    const int r = it >> 4, g = it & 15;
    const int4 m4 = *(const int4*)(Mg + (size_t)r * SS + g * 256 + lane * 4);
    const unsigned long long b0 = __ballot(m4.x != 0);
    const unsigned long long b1 = __ballot(m4.y != 0);
    const unsigned long long b2 = __ballot(m4.z != 0);
    const unsigned long long b3 = __ballot(m4.w != 0);
    if (lane == 0) {
      unsigned long long* dst = &Bm[r * 65 + (g << 2)];
      dst[0] = b0; dst[1] = b1; dst[2] = b2; dst[3] = b3;
    }
  }
  __syncthreads();

  // persistent A-fragments (Q rows for this wave's strip)
  const short8v aq0 = *(const short8v*)&Qs[qs + l15][quad * 8];
  const short8v aq1 = *(const short8v*)&Qs[qs + l15][32 + quad * 8];

  // ---- one-time gather: this lane's 256 mask bits -> 4 u64 VGPRs ----
  // col c = kt*64 + kq + l15 -> word Bm[row*65 + (kt>>2)*4 + (l15&3)],
  // bit (kt&3)*16 + (kq>>2) + (l15>>2).  After >>B0, bits sit at {0,16,32,48};
  // two shift-or folds compact them to a nibble; mreg[r] bit kt = masked.
  const int B0 = (kq >> 2) + (l15 >> 2);
  unsigned long long mreg[4];
#pragma unroll
  for (int rr = 0; rr < 4; ++rr) {
    const int row = qs + quad * 4 + rr;
    unsigned long long acc = 0ULL;
#pragma unroll
    for (int w16 = 0; w16 < 16; ++w16) {
      unsigned long long x = Bm[row * 65 + (w16 << 2) + (l15 & 3)] >> B0;
      x &= 0x0001000100010001ULL;
      x |= x >> 15;
      x |= x >> 30;
      acc |= (x & 0xFULL) << (w16 << 2);
    }
    mreg[rr] = acc;
  }
  __syncthreads();  // all gathers done -> Bm region (Ks0/Ks1) reusable

  // write deferred K tile 0 into Ks0
  *(short4v*)&Ks0[rK][cK] = pack4(pk0A);
  *(short4v*)&Ks0[rK + 32][cK] = pack4(pk0B);
  __syncthreads();

  // ================= sweep 1: row sums (1 barrier/kt, K dbuf) =================
  float rsum[4] = {0.f, 0.f, 0.f, 0.f};
  for (int kt = 0; kt < NKT; ++kt) {
    Row72* Kc = (kt & 1) ? Ks1 : Ks0;
    Row72* Kn = (kt & 1) ? Ks0 : Ks1;
    const int ktn = (kt + 1) & (NKT - 1);  // wrap: kt=63 restages tile0 for sweep2
    // issue next-tile loads early (land under the compute below)
    const float4 kA = *(const float4*)(Kg + (size_t)(ktn * KTILE + rK) * DD + cK);
    const float4 kB = *(const float4*)(Kg + (size_t)(ktn * KTILE + 32 + rK) * DD + cK);
    // QK on current buffer
    const short8v b0 = *(const short8v*)&Kc[kq + l15][quad * 8];
    const short8v b1 = *(const short8v*)&Kc[kq + l15][32 + quad * 8];
    float4v acc = {0.f, 0.f, 0.f, 0.f};
    acc = __builtin_amdgcn_mfma_f32_16x16x32_bf16(aq0, b0, acc, 0, 0, 0);
    acc = __builtin_amdgcn_mfma_f32_16x16x32_bf16(aq1, b1, acc, 0, 0, 0);
#pragma unroll
    for (int rr = 0; rr < 4; ++rr) {
      const bool msk = (mreg[rr] >> kt) & 1ULL;
      const float p = msk ? 0.f : __expf(acc[rr] * 0.125f);
      rsum[rr] += p;
    }
    // write prefetched tile (vmcnt mostly drained by now)
    *(short4v*)&Kn[rK][cK] = pack4(kA);
    *(short4v*)&Kn[rK + 32][cK] = pack4(kB);
    __syncthreads();
  }

  // reduce row sums: 16 lanes (l15) share each row; 4 waves share a row -> LDS atomic
#pragma unroll
  for (int rr = 0; rr < 4; ++rr) {
    float v = rsum[rr];
    v += __shfl_xor(v, 1);
    v += __shfl_xor(v, 2);
    v += __shfl_xor(v, 4);
    v += __shfl_xor(v, 8);
    if (l15 == 0) atomicAdd(&RowSum[qs + quad * 4 + rr], v);
  }
  __syncthreads();
  if (tid < QT) {
    const float s = RowSum[tid];
    InvRow[tid] = (s != 0.f) ? 1.f / s : 0.f;
  }
  __syncthreads();
  float inv[4];
#pragma unroll
  for (int rr = 0; rr < 4; ++rr) inv[rr] = InvRow[qs + quad * 4 + rr];

  // ================= sweep 2: attn write + PV (2 barriers/kt) =================
  // Ks0 already holds tile 0 (sweep1's wrap-around prefetch).
  float4v cacc = {0.f, 0.f, 0.f, 0.f};
  const int d0 = w << 3;
  for (int kt = 0; kt < NKT; ++kt) {
    Row72* Kc = (kt & 1) ? Ks1 : Ks0;
    Row72* Kn = (kt & 1) ? Ks0 : Ks1;
    const int ktn = (kt + 1) & (NKT - 1);
    // V loads for CURRENT tile first (consumed this iteration)
    const float4 vA = *(const float4*)(Vg + (size_t)(kt * KTILE + lane) * DD + d0);
    const float4 vB = *(const float4*)(Vg + (size_t)(kt * KTILE + lane) * DD + d0 + 4);
    // K loads for NEXT tile
    const float4 kA = *(const float4*)(Kg + (size_t)(ktn * KTILE + rK) * DD + cK);
    const float4 kB = *(const float4*)(Kg + (size_t)(ktn * KTILE + 32 + rK) * DD + cK);
    // QK (recompute) + attn write + P -> LDS
    const short8v b0 = *(const short8v*)&Kc[kq + l15][quad * 8];
    const short8v b1 = *(const short8v*)&Kc[kq + l15][32 + quad * 8];
    float4v acc = {0.f, 0.f, 0.f, 0.f};
    acc = __builtin_amdgcn_mfma_f32_16x16x32_bf16(aq0, b0, acc, 0, 0, 0);
    acc = __builtin_amdgcn_mfma_f32_16x16x32_bf16(aq1, b1, acc, 0, 0, 0);
#pragma unroll
    for (int rr = 0; rr < 4; ++rr) {
      const int row = qs + quad * 4 + rr;
      const bool msk = (mreg[rr] >> kt) & 1ULL;
      const float p = msk ? 0.f : __expf(acc[rr] * 0.125f);
      Ps[row][kq + l15] = f2bf(p);                          // unnormalized P for PV
      Ag[(size_t)row * SS + kt * KTILE + kq + l15] = p * inv[rr];  // normalized attn
    }
    // V tile -> LDS transposed (waits on V loads only; K loads stay in flight)
    Vt[d0 + 0][lane] = f2bf(vA.x);
    Vt[d0 + 1][lane] = f2bf(vA.y);
    Vt[d0 + 2][lane] = f2bf(vA.z);
    Vt[d0 + 3][lane] = f2bf(vA.w);
    Vt[d0 + 4][lane] = f2bf(vB.x);
    Vt[d0 + 5][lane] = f2bf(vB.y);
    Vt[d0 + 6][lane] = f2bf(vB.z);
    Vt[d0 + 7][lane] = f2bf(vB.w);
    __syncthreads();
    // PV: context[q][d] += P[q][kk] * V[kk][d]
#pragma unroll
    for (int ks = 0; ks < 2; ++ks) {
      const short8v ap = *(const short8v*)&Ps[qs + l15][ks * 32 + quad * 8];
      const short8v bv = *(const short8v*)&Vt[dq + l15][ks * 32 + quad * 8];
      cacc = __builtin_amdgcn_mfma_f32_16x16x32_bf16(ap, bv, cacc, 0, 0, 0);
    }
    // write prefetched K tile
    *(short4v*)&Kn[rK][cK] = pack4(kA);
    *(short4v*)&Kn[rK + 32][cK] = pack4(kB);
    __syncthreads();
  }

  // context epilogue (normalize at the end)
#pragma unroll
  for (int rr = 0; rr < 4; ++rr) {
    const int row = qs + quad * 4 + rr;
    Cg[(size_t)row * DD + dq + l15] = cacc[rr] * inv[rr];
  }
}

extern "C" void kernel_launch(void* const* d_in, const int* in_sizes, int n_in,
                              void* d_out, int out_size, void* d_ws, size_t ws_size,
                              hipStream_t stream) {
  const float* q = (const float*)d_in[0];
  const float* k = (const float*)d_in[1];
  const float* v = (const float*)d_in[2];
  const int*   m = (const int*)d_in[3];
  float* ctx  = (float*)d_out;                        // [B,S,D] first output
  float* attn = (float*)d_out + (size_t)BB * SS * DD; // [B,S,S] second output
  dim3 grid(BB * (SS / QT));  // 1024 blocks
  attn_fused_kernel<<<grid, NTHREADS, 0, stream>>>(q, k, v, m, ctx, attn);
}